// Round 2
// baseline (7099.242 us; speedup 1.0000x reference)
//
#include <hip/hip_runtime.h>
#include <hip/hip_bf16.h>

typedef __attribute__((ext_vector_type(8))) short  short8;   // 8 x bf16 (MFMA frag)
typedef __attribute__((ext_vector_type(4))) float  f32x4;
typedef __attribute__((ext_vector_type(2))) unsigned int uint2v;

#define N_SP   512
#define N_CD   1024
#define NSTEPS 100
#define HSTEP  0.2f

// ---- RK45 (Dormand-Prince) coefficients, rounded to f32 like the reference ----
#define A21 (0.2f)
#define A31 (3.0f/40.0f)
#define A32 (9.0f/40.0f)
#define A41 (44.0f/45.0f)
#define A42 (-56.0f/15.0f)
#define A43 (32.0f/9.0f)
#define A51 (19372.0f/6561.0f)
#define A52 (-25360.0f/2187.0f)
#define A53 (64448.0f/6561.0f)
#define A54 (-212.0f/729.0f)
#define A61 (9017.0f/3168.0f)
#define A62 (-355.0f/33.0f)
#define A63 (46732.0f/5247.0f)
#define A64 (49.0f/176.0f)
#define A65 (-5103.0f/18656.0f)
#define B1  (35.0f/384.0f)
#define B3  (500.0f/1113.0f)
#define B4  (125.0f/192.0f)
#define B5  (-2187.0f/6784.0f)
#define B6  (11.0f/84.0f)

__device__ __forceinline__ unsigned short f2bf(float f) {
    union { float f; unsigned u; } v; v.f = f;
    unsigned r = v.u + 0x7FFFu + ((v.u >> 16) & 1u);   // RNE
    return (unsigned short)(r >> 16);
}

// Pack A (f32 row-major [row][k]) into bf16 in exact MFMA A-fragment stream order:
// slot q = ((T*16 + kk)*64 + lane); holds A[T*16 + (lane&15)][kk*32 + (lane>>4)*8 + 0..7]
__global__ void pack_A_kernel(const float* __restrict__ A, short* __restrict__ Aw) {
    int q    = blockIdx.x * blockDim.x + threadIdx.x;   // 0..32767
    int lane = q & 63;
    int fk   = q >> 6;            // (T<<4) | kk
    int kk   = fk & 15;
    int T    = fk >> 4;
    int row  = T * 16 + (lane & 15);
    int kb   = kk * 32 + (lane >> 4) * 8;
    const float* src = A + row * 512 + kb;
    short8 v;
#pragma unroll
    for (int e = 0; e < 8; ++e) v[e] = (short)f2bf(src[e]);
    *(short8*)(Aw + (size_t)q * 8) = v;
}

// One RK stage: Yv (f32 regs, this wave's 64 rows x 16 cols) -> LDS bf16 -> Z=A@Y -> Ko = Yv*(W+Z)
__device__ __forceinline__ void do_stage(
    const f32x4 (&Yv)[4], f32x4 (&Ko)[4], const f32x4 (&W)[4],
    char* Ylds, const short* Alane,
    int wave, int gq, int cl, int swz)
{
    char* Ywr = Ylds + cl * 1024;
#pragma unroll
    for (int t = 0; t < 4; ++t) {
        int rb = wave * 64 + t * 16 + gq * 4;   // 4 consecutive rows per lane (C-frag layout)
        uint2v u;
        u.x = (unsigned)f2bf(Yv[t][0]) | ((unsigned)f2bf(Yv[t][1]) << 16);
        u.y = (unsigned)f2bf(Yv[t][2]) | ((unsigned)f2bf(Yv[t][3]) << 16);
        *(uint2v*)(Ywr + ((rb * 2) ^ swz)) = u;
    }
    __syncthreads();   // Y complete (all 8 waves' row blocks)

    f32x4 acc[4];
#pragma unroll
    for (int t = 0; t < 4; ++t) acc[t] = (f32x4){0.f, 0.f, 0.f, 0.f};

    const int g16 = gq * 16;
    short8 ab[2][8];
#pragma unroll
    for (int i = 0; i < 8; ++i)
        ab[0][i] = *(const short8*)(Alane + i * 512);
#pragma unroll
    for (int ch = 0; ch < 8; ++ch) {
        const int cur = ch & 1, nxt = cur ^ 1;
        if (ch < 7) {
#pragma unroll
            for (int i = 0; i < 8; ++i)
                ab[nxt][i] = *(const short8*)(Alane + ((ch + 1) * 8 + i) * 512);
        }
#pragma unroll
        for (int i = 0; i < 8; ++i) {
            const int f  = ch * 8 + i;
            const int t  = f >> 4;     // row tile within wave (0..3)
            const int kk = f & 15;     // K chunk (0..15)
            const short8 b = *(const short8*)(Ylds + cl * 1024 + ((kk * 64 + g16) ^ swz));
            acc[t] = __builtin_amdgcn_mfma_f32_16x16x32_bf16(ab[cur][i], b, acc[t], 0, 0, 0);
        }
    }
    __syncthreads();   // everyone done reading Ylds before next stage overwrites
#pragma unroll
    for (int t = 0; t < 4; ++t)
        Ko[t] = Yv[t] * (W[t] + acc[t]);
}

__global__ __launch_bounds__(512, 2) void mbpert_kernel(
    const float* __restrict__ x, const float* __restrict__ p,
    const float* __restrict__ r, const float* __restrict__ eps,
    const short* __restrict__ Aw, float* __restrict__ out)
{
    __shared__ __align__(16) char Ylds[16 * 1024];  // 16 cols x 512 rows bf16, XOR-swizzled

    const int g    = blockIdx.x;       // column group: cols [g*16, g*16+16)
    const int tid  = threadIdx.x;
    const int wave = tid >> 6;         // 0..7, owns rows [wave*64, wave*64+64)
    const int lane = tid & 63;
    const int cl   = lane & 15;        // MFMA col / C-frag col
    const int gq   = lane >> 4;        // quad group
    const int col  = g * 16 + cl;
    const int swz  = (cl & 7) << 4;    // 3-bit LDS XOR swizzle (bits 4-6)

    const short* Alane = Aw + wave * 32768 + lane * 8;  // wave's 64-row A block, frag-ordered

    // persistent per-lane state: 4 frags x 4 rows (C-frag layout: row = rb+j, col = cl)
    f32x4 X0[4], W[4], K[6][4], Yv[4];
#pragma unroll
    for (int t = 0; t < 4; ++t) {
        const int rb = wave * 64 + t * 16 + gq * 4;
        X0[t] = *(const f32x4*)(x + col * 512 + rb);    // Fortran: x[col*512+row]
#pragma unroll
        for (int j = 0; j < 4; ++j) {
            const int row = rb + j;
            W[t][j] = r[row] + eps[row] * p[row * 1024 + col];  // r + eps*p (stage-invariant)
        }
    }

#pragma unroll 1
    for (int s = 0; s < NSTEPS; ++s) {
#pragma unroll
        for (int t = 0; t < 4; ++t) Yv[t] = X0[t];
        do_stage(Yv, K[0], W, Ylds, Alane, wave, gq, cl, swz);

#pragma unroll
        for (int t = 0; t < 4; ++t) Yv[t] = X0[t] + HSTEP * (A21 * K[0][t]);
        do_stage(Yv, K[1], W, Ylds, Alane, wave, gq, cl, swz);

#pragma unroll
        for (int t = 0; t < 4; ++t) Yv[t] = X0[t] + HSTEP * (A31 * K[0][t] + A32 * K[1][t]);
        do_stage(Yv, K[2], W, Ylds, Alane, wave, gq, cl, swz);

#pragma unroll
        for (int t = 0; t < 4; ++t) Yv[t] = X0[t] + HSTEP * (A41 * K[0][t] + A42 * K[1][t] + A43 * K[2][t]);
        do_stage(Yv, K[3], W, Ylds, Alane, wave, gq, cl, swz);

#pragma unroll
        for (int t = 0; t < 4; ++t) Yv[t] = X0[t] + HSTEP * (A51 * K[0][t] + A52 * K[1][t] + A53 * K[2][t] + A54 * K[3][t]);
        do_stage(Yv, K[4], W, Ylds, Alane, wave, gq, cl, swz);

#pragma unroll
        for (int t = 0; t < 4; ++t) Yv[t] = X0[t] + HSTEP * (A61 * K[0][t] + A62 * K[1][t] + A63 * K[2][t] + A64 * K[3][t] + A65 * K[4][t]);
        do_stage(Yv, K[5], W, Ylds, Alane, wave, gq, cl, swz);

#pragma unroll
        for (int t = 0; t < 4; ++t)
            X0[t] = X0[t] + HSTEP * (B1 * K[0][t] + B3 * K[2][t] + B4 * K[3][t] + B5 * K[4][t] + B6 * K[5][t]);
    }

    // out[col*512 + row] = X_final (Fortran flatten, same as input layout)
#pragma unroll
    for (int t = 0; t < 4; ++t) {
        const int rb = wave * 64 + t * 16 + gq * 4;
        *(f32x4*)(out + col * 512 + rb) = X0[t];
    }
}

extern "C" void kernel_launch(void* const* d_in, const int* in_sizes, int n_in,
                              void* d_out, int out_size, void* d_ws, size_t ws_size,
                              hipStream_t stream)
{
    const float* x   = (const float*)d_in[0];
    const float* p   = (const float*)d_in[1];
    const float* r   = (const float*)d_in[2];
    const float* A   = (const float*)d_in[3];
    const float* eps = (const float*)d_in[4];
    float* out = (float*)d_out;
    short* Aw  = (short*)d_ws;   // 512 KB bf16 repacked A

    hipLaunchKernelGGL(pack_A_kernel, dim3(128), dim3(256), 0, stream, A, Aw);
    hipLaunchKernelGGL(mbpert_kernel, dim3(64), dim3(512), 0, stream,
                       x, p, r, eps, Aw, out);
}

// Round 3
// 6279.197 us; speedup vs baseline: 1.1306x; 1.1306x over previous
//
#include <hip/hip_runtime.h>
#include <hip/hip_bf16.h>

typedef __attribute__((ext_vector_type(8))) short  short8;   // 8 x bf16 (MFMA frag)
typedef __attribute__((ext_vector_type(4))) float  f32x4;
typedef __attribute__((ext_vector_type(2))) unsigned int uint2v;

#define N_SP   512
#define N_CD   1024
#define NSTEPS 100
#define HSTEP  0.2f

// ---- RK45 (Dormand-Prince) coefficients, rounded to f32 like the reference ----
#define A21 (0.2f)
#define A31 (3.0f/40.0f)
#define A32 (9.0f/40.0f)
#define A41 (44.0f/45.0f)
#define A42 (-56.0f/15.0f)
#define A43 (32.0f/9.0f)
#define A51 (19372.0f/6561.0f)
#define A52 (-25360.0f/2187.0f)
#define A53 (64448.0f/6561.0f)
#define A54 (-212.0f/729.0f)
#define A61 (9017.0f/3168.0f)
#define A62 (-355.0f/33.0f)
#define A63 (46732.0f/5247.0f)
#define A64 (49.0f/176.0f)
#define A65 (-5103.0f/18656.0f)
#define B1  (35.0f/384.0f)
#define B3  (500.0f/1113.0f)
#define B4  (125.0f/192.0f)
#define B5  (-2187.0f/6784.0f)
#define B6  (11.0f/84.0f)

__device__ __forceinline__ unsigned short f2bf(float f) {
    union { float f; unsigned u; } v; v.f = f;
    unsigned r = v.u + 0x7FFFu + ((v.u >> 16) & 1u);   // RNE
    return (unsigned short)(r >> 16);
}

// Pack A (f32 row-major [row][k]) into bf16 in exact MFMA A-fragment stream order:
// slot q = ((T*16 + kk)*64 + lane); holds A[T*16 + (lane&15)][kk*32 + (lane>>4)*8 + 0..7]
__global__ void pack_A_kernel(const float* __restrict__ A, short* __restrict__ Aw) {
    int q    = blockIdx.x * blockDim.x + threadIdx.x;   // 0..32767
    int lane = q & 63;
    int fk   = q >> 6;            // (T<<4) | kk
    int kk   = fk & 15;
    int T    = fk >> 4;
    int row  = T * 16 + (lane & 15);
    int kb   = kk * 32 + (lane >> 4) * 8;
    const float* src = A + row * 512 + kb;
    short8 v;
#pragma unroll
    for (int e = 0; e < 8; ++e) v[e] = (short)f2bf(src[e]);
    *(short8*)(Aw + (size_t)q * 8) = v;
}

// One matmul stage: Yv (f32 regs, wave's 64 rows x 16 cols) -> LDS bf16 -> acc = A@Y
__device__ __forceinline__ void mm_stage(
    const f32x4 (&Yv)[4], f32x4 (&acc)[4],
    char* Ylds, const short* Alane,
    int wave, int gq, int cl, int swz)
{
    char* Ywr = Ylds + cl * 1024;
#pragma unroll
    for (int t = 0; t < 4; ++t) {
        int rb = wave * 64 + t * 16 + gq * 4;   // 4 consecutive rows per lane (C-frag layout)
        uint2v u;
        u.x = (unsigned)f2bf(Yv[t][0]) | ((unsigned)f2bf(Yv[t][1]) << 16);
        u.y = (unsigned)f2bf(Yv[t][2]) | ((unsigned)f2bf(Yv[t][3]) << 16);
        *(uint2v*)(Ywr + ((rb * 2) ^ swz)) = u;
    }
    __syncthreads();   // Y complete (all 8 waves' row blocks)

#pragma unroll
    for (int t = 0; t < 4; ++t) acc[t] = (f32x4){0.f, 0.f, 0.f, 0.f};

    const int g16 = gq * 16;
    short8 ab[2][8];
#pragma unroll
    for (int i = 0; i < 8; ++i)
        ab[0][i] = *(const short8*)(Alane + i * 512);
#pragma unroll
    for (int ch = 0; ch < 8; ++ch) {
        const int cur = ch & 1, nxt = cur ^ 1;
        if (ch < 7) {
#pragma unroll
            for (int i = 0; i < 8; ++i)
                ab[nxt][i] = *(const short8*)(Alane + ((ch + 1) * 8 + i) * 512);
        }
#pragma unroll
        for (int i = 0; i < 8; ++i) {
            const int f  = ch * 8 + i;
            const int t  = f >> 4;     // row tile within wave (0..3)
            const int kk = f & 15;     // K chunk (0..15)
            const short8 b = *(const short8*)(Ylds + cl * 1024 + ((kk * 64 + g16) ^ swz));
            acc[t] = __builtin_amdgcn_mfma_f32_16x16x32_bf16(ab[cur][i], b, acc[t], 0, 0, 0);
        }
    }
    __syncthreads();   // everyone done reading Ylds before next stage overwrites
}

__global__ __launch_bounds__(512, 2) __attribute__((amdgpu_waves_per_eu(2, 2)))
void mbpert_kernel(
    const float* __restrict__ x, const float* __restrict__ p,
    const float* __restrict__ r, const float* __restrict__ eps,
    const short* __restrict__ Aw, float* __restrict__ out)
{
    __shared__ __align__(16) char  Ylds[16 * 1024];   // 16 cols x 512 rows bf16, XOR-swizzled
    __shared__ __align__(16) f32x4 Klds[3 * 4 * 512]; // 96 KB: K1..K3 f32, [j][tile][tid] private slots

    const int g    = blockIdx.x;       // column group: cols [g*16, g*16+16)
    const int tid  = threadIdx.x;
    const int wave = tid >> 6;         // 0..7, owns rows [wave*64, wave*64+64)
    const int lane = tid & 63;
    const int cl   = lane & 15;        // MFMA col / C-frag col
    const int gq   = lane >> 4;        // quad group
    const int col  = g * 16 + cl;
    const int swz  = (cl & 7) << 4;    // 3-bit LDS XOR swizzle (bits 4-6)

    const short* Alane = Aw + wave * 32768 + lane * 8;  // wave's 64-row A block, frag-ordered
    f32x4* kbase = &Klds[tid];                          // + j*2048 + t*512

#define KSLOT(j, t) kbase[(j) * 2048 + (t) * 512]

    // persistent per-lane state (C-frag layout: row = rb+jj, col = cl)
    f32x4 X0[4], W[4], Kr4[4], Kr5[4], Yv[4], acc[4];
#pragma unroll
    for (int t = 0; t < 4; ++t) {
        const int rb = wave * 64 + t * 16 + gq * 4;
        X0[t] = *(const f32x4*)(x + col * 512 + rb);    // Fortran: x[col*512+row]
#pragma unroll
        for (int j = 0; j < 4; ++j) {
            const int row = rb + j;
            W[t][j] = r[row] + eps[row] * p[row * 1024 + col];  // r + eps*p (stage-invariant)
        }
    }

#pragma unroll 1
    for (int s = 0; s < NSTEPS; ++s) {
        // ---- stage 1: Y = X0 ; K1 -> LDS ----
#pragma unroll
        for (int t = 0; t < 4; ++t) Yv[t] = X0[t];
        mm_stage(Yv, acc, Ylds, Alane, wave, gq, cl, swz);
#pragma unroll
        for (int t = 0; t < 4; ++t) KSLOT(0, t) = Yv[t] * (W[t] + acc[t]);

        // ---- stage 2: Y = X0 + h*A21*K1 ; K2 -> LDS ----
#pragma unroll
        for (int t = 0; t < 4; ++t) {
            f32x4 k1 = KSLOT(0, t);
            Yv[t] = X0[t] + HSTEP * (A21 * k1);
        }
        mm_stage(Yv, acc, Ylds, Alane, wave, gq, cl, swz);
#pragma unroll
        for (int t = 0; t < 4; ++t) KSLOT(1, t) = Yv[t] * (W[t] + acc[t]);

        // ---- stage 3 ; K3 -> LDS ----
#pragma unroll
        for (int t = 0; t < 4; ++t) {
            f32x4 k1 = KSLOT(0, t), k2 = KSLOT(1, t);
            Yv[t] = X0[t] + HSTEP * (A31 * k1 + A32 * k2);
        }
        mm_stage(Yv, acc, Ylds, Alane, wave, gq, cl, swz);
#pragma unroll
        for (int t = 0; t < 4; ++t) KSLOT(2, t) = Yv[t] * (W[t] + acc[t]);

        // ---- stage 4 ; K4 -> regs ----
#pragma unroll
        for (int t = 0; t < 4; ++t) {
            f32x4 k1 = KSLOT(0, t), k2 = KSLOT(1, t), k3 = KSLOT(2, t);
            Yv[t] = X0[t] + HSTEP * (A41 * k1 + A42 * k2 + A43 * k3);
        }
        mm_stage(Yv, acc, Ylds, Alane, wave, gq, cl, swz);
#pragma unroll
        for (int t = 0; t < 4; ++t) Kr4[t] = Yv[t] * (W[t] + acc[t]);

        // ---- stage 5 ; K5 -> regs ----
#pragma unroll
        for (int t = 0; t < 4; ++t) {
            f32x4 k1 = KSLOT(0, t), k2 = KSLOT(1, t), k3 = KSLOT(2, t);
            Yv[t] = X0[t] + HSTEP * (A51 * k1 + A52 * k2 + A53 * k3 + A54 * Kr4[t]);
        }
        mm_stage(Yv, acc, Ylds, Alane, wave, gq, cl, swz);
#pragma unroll
        for (int t = 0; t < 4; ++t) Kr5[t] = Yv[t] * (W[t] + acc[t]);

        // ---- stage 6 ; K6 transient, fold into X0 update ----
#pragma unroll
        for (int t = 0; t < 4; ++t) {
            f32x4 k1 = KSLOT(0, t), k2 = KSLOT(1, t), k3 = KSLOT(2, t);
            Yv[t] = X0[t] + HSTEP * (A61 * k1 + A62 * k2 + A63 * k3 + A64 * Kr4[t] + A65 * Kr5[t]);
        }
        mm_stage(Yv, acc, Ylds, Alane, wave, gq, cl, swz);
#pragma unroll
        for (int t = 0; t < 4; ++t) {
            f32x4 k6 = Yv[t] * (W[t] + acc[t]);
            f32x4 k1 = KSLOT(0, t), k3 = KSLOT(2, t);
            X0[t] = X0[t] + HSTEP * (B1 * k1 + B3 * k3 + B4 * Kr4[t] + B5 * Kr5[t] + B6 * k6);
        }
    }

    // out[col*512 + row] = X_final (Fortran flatten, same as input layout)
#pragma unroll
    for (int t = 0; t < 4; ++t) {
        const int rb = wave * 64 + t * 16 + gq * 4;
        *(f32x4*)(out + col * 512 + rb) = X0[t];
    }
#undef KSLOT
}

extern "C" void kernel_launch(void* const* d_in, const int* in_sizes, int n_in,
                              void* d_out, int out_size, void* d_ws, size_t ws_size,
                              hipStream_t stream)
{
    const float* x   = (const float*)d_in[0];
    const float* p   = (const float*)d_in[1];
    const float* r   = (const float*)d_in[2];
    const float* A   = (const float*)d_in[3];
    const float* eps = (const float*)d_in[4];
    float* out = (float*)d_out;
    short* Aw  = (short*)d_ws;   // 512 KB bf16 repacked A

    hipLaunchKernelGGL(pack_A_kernel, dim3(128), dim3(256), 0, stream, A, Aw);
    hipLaunchKernelGGL(mbpert_kernel, dim3(64), dim3(512), 0, stream,
                       x, p, r, eps, Aw, out);
}